// Round 1
// baseline (349.084 us; speedup 1.0000x reference)
//
#include <hip/hip_runtime.h>
#include <hip/hip_bf16.h>

#define DEVI __device__ __forceinline__

typedef unsigned short u16;
typedef unsigned int u32;
typedef short short8 __attribute__((ext_vector_type(8)));
typedef float f32x4 __attribute__((ext_vector_type(4)));

#define TT 2048
#define CC 1024
#define NQKV 3072
#define AHAT_B 6291456ll
#define KTD_B 2097152ll
#define VHT_B 3145728ll
#define OBUF_B 2097152ll
#define RI_B 1048576ll

DEVI u16 f2bf(float f) {
  union { float f; u32 u; } v; v.f = f;
  u32 u = v.u;
  u32 r = (u + 0x7fffu + ((u >> 16) & 1u)) >> 16;
  return (u16)r;
}

DEVI void gload16(const u16* g, u16* l) {
  __builtin_amdgcn_global_load_lds(
      (__attribute__((address_space(1))) void*)(u16*)g,
      (__attribute__((address_space(3))) void*)l, 16, 0, 0);
}

// 128x128 tile, BK=32, 4 waves (2x2 of 64x64), m97 2-barrier structure.
DEVI void gemm_kloop(const u16* __restrict__ A, int lda,
                     const u16* __restrict__ Bt, int ldb,
                     int m0, int n0, int kt0, int kt1,
                     u16* As, u16* Bs, f32x4 acc[4][4],
                     int lane, int wv, int wr, int wc)
{
  const int fr = lane & 15, fq = lane >> 4;
  for (int kt = kt0; kt < kt1; ++kt) {
    const int k0 = kt << 5;
#pragma unroll
    for (int i = 0; i < 2; ++i) {
      const int seg = i * 4 + wv;                  // 0..7 (1024B segments)
      const int fe = seg * 512 + lane * 8;         // flat elem in 128x32 tile
      const int r = fe >> 5, kk = fe & 31;
      gload16(A + (size_t)(m0 + r) * lda + (k0 + kk), As + seg * 512);
      gload16(Bt + (size_t)(n0 + r) * ldb + (k0 + kk), Bs + seg * 512);
    }
    __syncthreads();
    short8 av[4], bv[4];
#pragma unroll
    for (int m = 0; m < 4; ++m)
      av[m] = *(const short8*)(As + (wr * 64 + m * 16 + fr) * 32 + fq * 8);
#pragma unroll
    for (int n = 0; n < 4; ++n)
      bv[n] = *(const short8*)(Bs + (wc * 64 + n * 16 + fr) * 32 + fq * 8);
#pragma unroll
    for (int m = 0; m < 4; ++m)
#pragma unroll
      for (int n = 0; n < 4; ++n)
        acc[m][n] = __builtin_amdgcn_mfma_f32_16x16x32_bf16(av[m], bv[n], acc[m][n], 0, 0, 0);
    __syncthreads();
  }
}

#define GEMM_PROLOG                                        \
  __shared__ alignas(16) u16 As[4096];                     \
  __shared__ alignas(16) u16 Bs[4096];                     \
  const int tid = threadIdx.x;                             \
  const int lane = tid & 63, wv = tid >> 6;                \
  const int wr = wv >> 1, wc = wv & 1;                     \
  const int fr = lane & 15, fq = lane >> 4;                \
  const f32x4 fzero = {0.f, 0.f, 0.f, 0.f};                \
  f32x4 acc[4][4];                                         \
  for (int m = 0; m < 4; ++m)                              \
    for (int n = 0; n < 4; ++n) acc[m][n] = fzero;

// ---------------- prep kernels ----------------

__global__ __launch_bounds__(256) void k_tables(float* __restrict__ costab,
                                                float* __restrict__ sintab,
                                                float* __restrict__ dpow)
{
  const int idx = blockIdx.x * 256 + threadIdx.x;
  if (idx < 2048 * 512) {
    const int t = idx >> 9, i = idx & 511;
    const float invf = expf(-0.017988946039015984f * (float)i); // 10000^(-i/512)
    const float ang = (float)t * invf;
    costab[idx] = cosf(ang);
    sintab[idx] = sinf(ang);
  }
  if (idx < 2080) dpow[idx] = exp2f(-0.04580368618911996f * (float)idx); // gamma^idx
}

__global__ __launch_bounds__(256) void k_convert(const float* __restrict__ src,
                                                 u16* __restrict__ dst)
{
  const size_t i4 = (size_t)blockIdx.x * 256 + threadIdx.x;
  const float4 v = *(const float4*)(src + i4 * 4);
  ushort4 o;
  o.x = f2bf(v.x); o.y = f2bf(v.y); o.z = f2bf(v.z); o.w = f2bf(v.w);
  *(ushort4*)(dst + i4 * 4) = o;
}

// src: 1024x1024 fp32 row-major -> dst[c][r] bf16 with leading dim ldd
__global__ __launch_bounds__(256) void k_transpose(const float* __restrict__ src,
                                                   u16* __restrict__ dst, int ldd)
{
  __shared__ float tile[64][65];
  const int r0 = blockIdx.y * 64, c0 = blockIdx.x * 64;
  const int tid = threadIdx.x;
  const int tr = tid >> 4;
  const int tc = (tid & 15) * 4;
#pragma unroll
  for (int k = 0; k < 4; ++k) {
    const float4 v = *(const float4*)(src + (size_t)(r0 + tr + 16 * k) * 1024 + c0 + tc);
    tile[tr + 16 * k][tc + 0] = v.x;
    tile[tr + 16 * k][tc + 1] = v.y;
    tile[tr + 16 * k][tc + 2] = v.z;
    tile[tr + 16 * k][tc + 3] = v.w;
  }
  __syncthreads();
#pragma unroll
  for (int k = 0; k < 4; ++k) {
    const int n = tr + 16 * k;
    ushort4 o;
    o.x = f2bf(tile[tc + 0][n]);
    o.y = f2bf(tile[tc + 1][n]);
    o.z = f2bf(tile[tc + 2][n]);
    o.w = f2bf(tile[tc + 3][n]);
    *(ushort4*)(dst + (size_t)(c0 + n) * ldd + r0 + tc) = o;
  }
}

// ---------------- GEMM kernels ----------------

// C = Xb(8192x1024) @ WQKVt^T(3072x1024): rope epilogue, writes Q,K,Ktd,VhatT,Qe
__global__ __launch_bounds__(256) void k_gemm_qkv(
    const u16* __restrict__ Xb, const u16* __restrict__ Wt,
    u16* __restrict__ Qb, u16* __restrict__ Kb, u16* __restrict__ Ktd,
    u16* __restrict__ VhatT, u16* __restrict__ Ahat,
    const float* __restrict__ costab, const float* __restrict__ sintab,
    const float* __restrict__ dpow)
{
  GEMM_PROLOG;
  const int n0 = blockIdx.x * 128, m0 = blockIdx.y * 128;
  gemm_kloop(Xb, CC, Wt, CC, m0, n0, 0, 32, As, Bs, acc, lane, wv, wr, wc);
#pragma unroll
  for (int n = 0; n < 4; ++n) {
    const int col = n0 + wc * 64 + n * 16 + fr;
#pragma unroll
    for (int m = 0; m < 4; ++m) {
      const int rowb = m0 + wr * 64 + m * 16 + fq * 4;
      f32x4 v = acc[m][n];
      const int bb = rowb >> 11;
      const int tb = rowb & 2047;
      if (col < 2048) {
        const int c = col & 1023;
        const int fi = c >> 1;
        const float sg = (col & 1) ? 1.0f : -1.0f;
        float y[4];
#pragma unroll
        for (int j = 0; j < 4; ++j) {
          const float other = __shfl_xor(v[j], 1);
          const int t = tb + j;
          const float cs = costab[t * 512 + fi];
          const float sn = sintab[t * 512 + fi];
          y[j] = v[j] * cs + sg * other * sn;
        }
        if (col < 1024) {
#pragma unroll
          for (int j = 0; j < 4; ++j) {
            const int R = rowb + j, t = tb + j;
            Qb[(size_t)R * CC + c] = f2bf(y[j]);
            Ahat[bb * AHAT_B + (size_t)t * NQKV + 2048 + c] = f2bf(y[j] * dpow[t + 1]);
          }
        } else {
#pragma unroll
          for (int j = 0; j < 4; ++j)
            Kb[(size_t)(rowb + j) * CC + c] = f2bf(y[j]);
          ushort4 pk;
          pk.x = f2bf(y[0] * dpow[2047 - tb]);
          pk.y = f2bf(y[1] * dpow[2046 - tb]);
          pk.z = f2bf(y[2] * dpow[2045 - tb]);
          pk.w = f2bf(y[3] * dpow[2044 - tb]);
          *(ushort4*)(Ktd + bb * KTD_B + (size_t)c * TT + tb) = pk;
        }
      } else {
        const int o = col - 2048;
        ushort4 pk;
        pk.x = f2bf(v[0]); pk.y = f2bf(v[1]); pk.z = f2bf(v[2]); pk.w = f2bf(v[3]);
        *(ushort4*)(VhatT + bb * VHT_B + (size_t)o * NQKV + tb) = pk;
      }
    }
  }
}

// A = (Q K^T) * D per batch, bf16 into Ahat[t][s]
__global__ __launch_bounds__(256) void k_gemm_a(
    const u16* __restrict__ Qb, const u16* __restrict__ Kb,
    u16* __restrict__ Ahat, const float* __restrict__ dpow)
{
  GEMM_PROLOG;
  const int b = blockIdx.z;
  const int n0 = blockIdx.x * 128, m0 = blockIdx.y * 128;
  if (n0 <= m0 + 127) {
    gemm_kloop(Qb + (size_t)b * 2097152, CC, Kb + (size_t)b * 2097152, CC,
               m0, n0, 0, 32, As, Bs, acc, lane, wv, wr, wc);
  }
  u16* Ab = Ahat + b * AHAT_B;
#pragma unroll
  for (int n = 0; n < 4; ++n) {
    const int s = n0 + wc * 64 + n * 16 + fr;
#pragma unroll
    for (int m = 0; m < 4; ++m) {
      const int rowb = m0 + wr * 64 + m * 16 + fq * 4;
      f32x4 v = acc[m][n];
#pragma unroll
      for (int j = 0; j < 4; ++j) {
        const int t = rowb + j;
        const float val = (s <= t) ? v[j] * dpow[t - s] : 0.f;
        Ab[(size_t)t * NQKV + s] = f2bf(val);
      }
    }
  }
}

// out = Ahat(2048x3072) @ VhatT^T(1024x3072) -> fp32 Obuf[t][o]
__global__ __launch_bounds__(256) void k_gemm_out(
    const u16* __restrict__ Ahat, const u16* __restrict__ VhatT,
    float* __restrict__ Obuf)
{
  GEMM_PROLOG;
  const int b = blockIdx.z;
  const int n0 = blockIdx.x * 128, m0 = blockIdx.y * 128;
  const u16* A = Ahat + b * AHAT_B;
  const u16* Bt = VhatT + b * VHT_B;
  const int kt1 = (m0 >> 5) + 4;   // only s <= t_max tiles are nonzero
  gemm_kloop(A, NQKV, Bt, NQKV, m0, n0, 0, kt1, As, Bs, acc, lane, wv, wr, wc);
  gemm_kloop(A, NQKV, Bt, NQKV, m0, n0, 64, 96, As, Bs, acc, lane, wv, wr, wc);
  float* Ob = Obuf + b * OBUF_B;
#pragma unroll
  for (int n = 0; n < 4; ++n) {
    const int col = n0 + wc * 64 + n * 16 + fr;
#pragma unroll
    for (int m = 0; m < 4; ++m) {
      const int rowb = m0 + wr * 64 + m * 16 + fq * 4;
      f32x4 v = acc[m][n];
#pragma unroll
      for (int j = 0; j < 4; ++j)
        Ob[(size_t)(rowb + j) * CC + col] = v[j];
    }
  }
}

// R_i = Ktd(1024x2048) @ Vt^T + gamma^T * S_n -> fp32 out1[c][o]
__global__ __launch_bounds__(256) void k_gemm_ri(
    const u16* __restrict__ Ktd, const u16* __restrict__ VhatT,
    const float* __restrict__ Sn, float* __restrict__ out1,
    const float* __restrict__ dpow)
{
  GEMM_PROLOG;
  const int b = blockIdx.z;
  const int n0 = blockIdx.x * 128, m0 = blockIdx.y * 128;
  gemm_kloop(Ktd + b * KTD_B, TT, VhatT + b * VHT_B, NQKV,
             m0, n0, 0, 64, As, Bs, acc, lane, wv, wr, wc);
  const float gT = dpow[2048];
  const float* Sb = Sn + b * RI_B;
  float* Rb = out1 + b * RI_B;
#pragma unroll
  for (int n = 0; n < 4; ++n) {
    const int col = n0 + wc * 64 + n * 16 + fr;
#pragma unroll
    for (int m = 0; m < 4; ++m) {
      const int rowb = m0 + wr * 64 + m * 16 + fq * 4;
      f32x4 v = acc[m][n];
#pragma unroll
      for (int j = 0; j < 4; ++j) {
        const size_t idx = (size_t)(rowb + j) * CC + col;
        Rb[idx] = v[j] + gT * Sb[idx];
      }
    }
  }
}

// ---------------- GroupNorm + transposed output ----------------
// out[b][c][t] = GN(Obuf[b][t][:])[c]
__global__ __launch_bounds__(256) void k_gn(
    const float* __restrict__ Obuf, const float* __restrict__ gw,
    const float* __restrict__ gb, float* __restrict__ out)
{
  __shared__ float L[32][1024];
  const int bi = blockIdx.x;
  const int b = bi >> 6;
  const int t0 = (bi & 63) << 5;
  const int tid = threadIdx.x;
  const int lane = tid & 63, wv = tid >> 6;
  float wgt[16], bsv[16];
#pragma unroll
  for (int k = 0; k < 4; ++k) {
    const float4 w4 = *(const float4*)(gw + k * 256 + lane * 4);
    const float4 b4 = *(const float4*)(gb + k * 256 + lane * 4);
    wgt[k*4+0]=w4.x; wgt[k*4+1]=w4.y; wgt[k*4+2]=w4.z; wgt[k*4+3]=w4.w;
    bsv[k*4+0]=b4.x; bsv[k*4+1]=b4.y; bsv[k*4+2]=b4.z; bsv[k*4+3]=b4.w;
  }
  for (int r = wv; r < 32; r += 4) {
    const float* src = Obuf + (size_t)(b * 2048 + t0 + r) * 1024;
#pragma unroll
    for (int k = 0; k < 4; ++k) {
      const float4 x = *(const float4*)(src + k * 256 + lane * 4);
      float s = x.x + x.y + x.z + x.w;
      float q = x.x*x.x + x.y*x.y + x.z*x.z + x.w*x.w;
      s += __shfl_xor(s, 1); q += __shfl_xor(q, 1);
      s += __shfl_xor(s, 2); q += __shfl_xor(q, 2);
      s += __shfl_xor(s, 4); q += __shfl_xor(q, 4);
      const float mu = s * 0.03125f;
      const float var = q * 0.03125f - mu * mu;
      const float rs = rsqrtf(var + 1e-6f);
      float4 y;
      y.x = (x.x - mu) * rs * wgt[k*4+0] + bsv[k*4+0];
      y.y = (x.y - mu) * rs * wgt[k*4+1] + bsv[k*4+1];
      y.z = (x.z - mu) * rs * wgt[k*4+2] + bsv[k*4+2];
      y.w = (x.w - mu) * rs * wgt[k*4+3] + bsv[k*4+3];
      *(float4*)&L[r][k * 256 + lane * 4] = y;
    }
  }
  __syncthreads();
  const size_t obase = (size_t)b * 2097152 + t0;
  for (int c = tid; c < 1024; c += 256) {
    float* dst = out + obase + (size_t)c * 2048;
#pragma unroll
    for (int i = 0; i < 8; ++i) {
      float4 o4;
      o4.x = L[i*4+0][c]; o4.y = L[i*4+1][c]; o4.z = L[i*4+2][c]; o4.w = L[i*4+3][c];
      *(float4*)(dst + i * 4) = o4;
    }
  }
}

// ---------------- launch ----------------

extern "C" void kernel_launch(void* const* d_in, const int* in_sizes, int n_in,
                              void* d_out, int out_size, void* d_ws, size_t ws_size,
                              hipStream_t stream)
{
  const float* XQ = (const float*)d_in[0];
  const float* Sn = (const float*)d_in[1];
  const float* WQ = (const float*)d_in[2];
  const float* WK = (const float*)d_in[3];
  const float* WV = (const float*)d_in[4];
  const float* gw = (const float*)d_in[5];
  const float* gb = (const float*)d_in[6];
  float* out0 = (float*)d_out;
  float* out1 = out0 + 8388608;

  char* ws = (char*)d_ws;
  u16* Xb      = (u16*)(ws);                  // 16 MB (dead after qkv; aliased by Obuf)
  u16* Qb      = (u16*)(ws + (16ll << 20));   // 16 MB (dead after gemm_a; aliased by Obuf)
  u16* Kb      = (u16*)(ws + (32ll << 20));   // 16 MB
  u16* Ktd     = (u16*)(ws + (48ll << 20));   // 16 MB
  u16* Ahat    = (u16*)(ws + (64ll << 20));   // 48 MB
  u16* VhatT   = (u16*)(ws + (112ll << 20));  // 24 MB
  u16* Wt      = (u16*)(ws + (136ll << 20));  // 6 MB
  float* costab = (float*)(ws + (142ll << 20)); // 4 MB
  float* sintab = (float*)(ws + (146ll << 20)); // 4 MB
  float* dpow   = (float*)(ws + (150ll << 20)); // ~8 KB
  float* Obuf   = (float*)(ws);               // 32 MB, aliases Xb+Qb (safe: both dead)

  k_tables<<<4096, 256, 0, stream>>>(costab, sintab, dpow);
  k_convert<<<8192, 256, 0, stream>>>(XQ, Xb);
  k_transpose<<<dim3(16, 16), 256, 0, stream>>>(WQ, Wt, 1024);
  k_transpose<<<dim3(16, 16), 256, 0, stream>>>(WK, Wt + 1048576, 1024);
  k_transpose<<<dim3(16, 16), 256, 0, stream>>>(WV, Wt + 2097152, 1024);
  for (int b = 0; b < 4; ++b)
    k_transpose<<<dim3(16, 16), 256, 0, stream>>>(Sn + (size_t)b * RI_B,
                                                  VhatT + (size_t)b * VHT_B + 2048, 3072);
  k_gemm_qkv<<<dim3(24, 64), 256, 0, stream>>>(Xb, Wt, Qb, Kb, Ktd, VhatT, Ahat,
                                               costab, sintab, dpow);
  k_gemm_a<<<dim3(16, 16, 4), 256, 0, stream>>>(Qb, Kb, Ahat, dpow);
  k_gemm_out<<<dim3(8, 16, 4), 256, 0, stream>>>(Ahat, VhatT, Obuf);
  k_gemm_ri<<<dim3(8, 8, 4), 256, 0, stream>>>(Ktd, VhatT, Sn, out1, dpow);
  k_gn<<<256, 256, 0, stream>>>(Obuf, gw, gb, out0);
}